// Round 2
// baseline (302.977 us; speedup 1.0000x reference)
//
#include <hip/hip_runtime.h>
#include <hip/hip_bf16.h>

typedef _Float16 half8 __attribute__((ext_vector_type(8)));
typedef _Float16 half4_t __attribute__((ext_vector_type(4)));
typedef float floatx4 __attribute__((ext_vector_type(4)));

#define MFMA16(a, b, c) __builtin_amdgcn_mfma_f32_16x16x32_f16(a, b, c, 0, 0, 0)
#define NEG_INF (-1e30f)

// 1/sqrt(128) * log2(e): scores land in log2 domain -> softmax uses exp2f
#define QSCALE 0.1275261529f

// ---------------------------------------------------------------------------
// Kernel 1: coalesced LDS-tiled transpose + fp32->fp16 convert.
// wq/wk/wv [1024][128] -> wqt/wkt/wvt [128][1024]; wo [128][1024] -> wot [1024][128].
// ---------------------------------------------------------------------------
__global__ __launch_bounds__(256) void transpose_convert(
    const float* __restrict__ wq, const float* __restrict__ wk,
    const float* __restrict__ wv, const float* __restrict__ wo,
    _Float16* __restrict__ wqt, _Float16* __restrict__ wkt,
    _Float16* __restrict__ wvt, _Float16* __restrict__ wot) {
  __shared__ float T[32][36];
  int bx = blockIdx.x, tid = threadIdx.x;
  const float* src;
  _Float16* dst;
  int R, C, r0, c0;
  if (bx < 384) {
    int p = bx >> 7, t = bx & 127;
    src = (p == 0) ? wq : (p == 1) ? wk : wv;
    dst = (p == 0) ? wqt : (p == 1) ? wkt : wvt;
    R = 1024; C = 128;
    r0 = (t & 31) * 32; c0 = (t >> 5) * 32;
  } else {
    int t = bx - 384;
    src = wo; dst = wot;
    R = 128; C = 1024;
    r0 = (t & 3) * 32; c0 = (t >> 2) * 32;
  }
  {
    int row = tid >> 3, c4 = (tid & 7) * 4;
    float4 f = *(const float4*)&src[(size_t)(r0 + row) * C + c0 + c4];
    T[row][c4] = f.x; T[row][c4 + 1] = f.y; T[row][c4 + 2] = f.z; T[row][c4 + 3] = f.w;
  }
  __syncthreads();
  {
    int cc = tid >> 3, r4 = (tid & 7) * 4;
    half4_t h;
    h[0] = (_Float16)T[r4 + 0][cc];
    h[1] = (_Float16)T[r4 + 1][cc];
    h[2] = (_Float16)T[r4 + 2][cc];
    h[3] = (_Float16)T[r4 + 3][cc];
    *(half4_t*)&dst[(size_t)(c0 + cc) * R + r0 + r4] = h;
  }
}

// ---------------------------------------------------------------------------
// Kernel 2: QKV projection, grid (128 m-tiles, 3 proj). 64 rows x 128 cols,
// BK=64. Q is pre-scaled by QSCALE. V written transposed Vt[(b*128+h)*2048+s].
// ---------------------------------------------------------------------------
__global__ __launch_bounds__(256) void qkv_gemm(
    const float* __restrict__ x, const _Float16* __restrict__ wqt,
    const _Float16* __restrict__ wkt, const _Float16* __restrict__ wvt,
    _Float16* __restrict__ Qh, _Float16* __restrict__ Kh,
    _Float16* __restrict__ Vt) {
  __shared__ _Float16 A_lds[64 * 72];
  __shared__ _Float16 B_lds[128 * 72];
  int tid = threadIdx.x;
  int w = tid >> 6, lane = tid & 63, quad = lane >> 4, l16 = lane & 15;
  int m0 = blockIdx.x * 64;
  int proj = blockIdx.y;
  const _Float16* wt = (proj == 0) ? wqt : (proj == 1) ? wkt : wvt;
  floatx4 zero = {0.f, 0.f, 0.f, 0.f};
  floatx4 acc[8];
#pragma unroll
  for (int t = 0; t < 8; t++) acc[t] = zero;

  int arow = tid >> 2, akk = (tid & 3) * 16;
  int bn = tid >> 1, bkk = (tid & 1) * 32;

  for (int k0 = 0; k0 < 1024; k0 += 64) {
    // A: 64x64 fp32 -> fp16
    {
      const float* s = x + (size_t)(m0 + arow) * 1024 + k0 + akk;
      float4 f0 = *(const float4*)(s);
      float4 f1 = *(const float4*)(s + 4);
      float4 f2 = *(const float4*)(s + 8);
      float4 f3 = *(const float4*)(s + 12);
      half8 h0, h1;
      h0[0] = (_Float16)f0.x; h0[1] = (_Float16)f0.y; h0[2] = (_Float16)f0.z; h0[3] = (_Float16)f0.w;
      h0[4] = (_Float16)f1.x; h0[5] = (_Float16)f1.y; h0[6] = (_Float16)f1.z; h0[7] = (_Float16)f1.w;
      h1[0] = (_Float16)f2.x; h1[1] = (_Float16)f2.y; h1[2] = (_Float16)f2.z; h1[3] = (_Float16)f2.w;
      h1[4] = (_Float16)f3.x; h1[5] = (_Float16)f3.y; h1[6] = (_Float16)f3.z; h1[7] = (_Float16)f3.w;
      *(half8*)&A_lds[arow * 72 + akk] = h0;
      *(half8*)&A_lds[arow * 72 + akk + 8] = h1;
    }
    // B: 128 n x 64 k
#pragma unroll
    for (int i = 0; i < 4; i++)
      *(half8*)&B_lds[bn * 72 + bkk + i * 8] =
          *(const half8*)&wt[(size_t)bn * 1024 + k0 + bkk + i * 8];
    __syncthreads();
    half8 a[2];
#pragma unroll
    for (int c = 0; c < 2; c++) a[c] = *(const half8*)&A_lds[(w * 16 + l16) * 72 + c * 32 + quad * 8];
#pragma unroll
    for (int t = 0; t < 8; t++)
#pragma unroll
      for (int c = 0; c < 2; c++) {
        half8 b = *(const half8*)&B_lds[(t * 16 + l16) * 72 + c * 32 + quad * 8];
        acc[t] = MFMA16(a[c], b, acc[t]);
      }
    __syncthreads();
  }
#pragma unroll
  for (int t = 0; t < 8; t++)
#pragma unroll
    for (int r = 0; r < 4; r++) {
      int row = m0 + w * 16 + quad * 4 + r;
      int col = t * 16 + l16;
      float v = acc[t][r];
      if (proj == 0)
        Qh[(size_t)row * 128 + col] = (_Float16)(v * QSCALE);
      else if (proj == 1)
        Kh[(size_t)row * 128 + col] = (_Float16)v;
      else {
        int bb = row >> 11, s = row & 2047;
        Vt[((size_t)(bb * 128 + col)) * 2048 + s] = (_Float16)v;
      }
    }
}

// ---------------------------------------------------------------------------
// Kernel 3: flash attention, one wave (64 thr) per 16 queries. 512 blocks,
// reverse-order launch (longest causal ranges first). No K/V LDS, no barriers:
// K/V fragments read directly from global (L2-resident). K-tile = 128 keys.
// ---------------------------------------------------------------------------
__global__ __launch_bounds__(64) void attn(
    const _Float16* __restrict__ Qh, const _Float16* __restrict__ Kh,
    const _Float16* __restrict__ Vt, _Float16* __restrict__ ctx) {
  __shared__ _Float16 P_lds[16 * 136];
  int lane = threadIdx.x, quad = lane >> 4, l16 = lane & 15;
  int g = (int)(gridDim.x - 1 - blockIdx.x);
  int b = g & 3, qw = g >> 2;
  int q0 = qw * 16;
  const _Float16* Kb = Kh + (size_t)b * 2048 * 128;
  const _Float16* Vb = Vt + (size_t)b * 128 * 2048;

  half8 aq[4];
  {
    const _Float16* qbase = Qh + (size_t)(b * 2048 + q0 + l16) * 128;
#pragma unroll
    for (int c = 0; c < 4; c++) aq[c] = *(const half8*)&qbase[c * 32 + quad * 8];
  }

  float m_r[4], l_r[4];
  floatx4 zero = {0.f, 0.f, 0.f, 0.f};
  floatx4 O[8];
#pragma unroll
  for (int r = 0; r < 4; r++) { m_r[r] = NEG_INF; l_r[r] = 0.f; }
#pragma unroll
  for (int t = 0; t < 8; t++) O[t] = zero;

  int nkt = q0 / 128 + 1;
  for (int kt = 0; kt < nkt; kt++) {
    int k0 = kt * 128;
    floatx4 sa[8];
#pragma unroll
    for (int t = 0; t < 8; t++) sa[t] = zero;
#pragma unroll
    for (int t = 0; t < 8; t++)
#pragma unroll
      for (int c = 0; c < 4; c++) {
        half8 bk = *(const half8*)&Kb[(size_t)(k0 + t * 16 + l16) * 128 + c * 32 + quad * 8];
        sa[t] = MFMA16(aq[c], bk, sa[t]);
      }

    bool last = (kt == nkt - 1);
    float p[8][4];
#pragma unroll
    for (int r = 0; r < 4; r++) {
      int query = q0 + quad * 4 + r;
      float mx = m_r[r];
#pragma unroll
      for (int t = 0; t < 8; t++) {
        float s = sa[t][r];
        if (last && (k0 + t * 16 + l16 > query)) s = NEG_INF;
        p[t][r] = s;
        mx = fmaxf(mx, s);
      }
#pragma unroll
      for (int off = 1; off < 16; off <<= 1) mx = fmaxf(mx, __shfl_xor(mx, off));
      float alpha = exp2f(m_r[r] - mx);
      float rs = 0.f;
#pragma unroll
      for (int t = 0; t < 8; t++) {
        float e = exp2f(p[t][r] - mx);
        p[t][r] = e;
        rs += e;
      }
#pragma unroll
      for (int off = 1; off < 16; off <<= 1) rs += __shfl_xor(rs, off);
      l_r[r] = alpha * l_r[r] + rs;
      m_r[r] = mx;
#pragma unroll
      for (int t = 0; t < 8; t++) O[t][r] *= alpha;
    }

    // P: C-layout -> LDS -> A-layout (wave-private; in-wave ds ordering)
#pragma unroll
    for (int r = 0; r < 4; r++)
#pragma unroll
      for (int t = 0; t < 8; t++)
        P_lds[(quad * 4 + r) * 136 + t * 16 + l16] = (_Float16)p[t][r];

#pragma unroll
    for (int c2 = 0; c2 < 4; c2++) {
      half8 ap = *(const half8*)&P_lds[l16 * 136 + c2 * 32 + quad * 8];
#pragma unroll
      for (int t = 0; t < 8; t++) {
        half8 bv = *(const half8*)&Vb[(size_t)(t * 16 + l16) * 2048 + k0 + c2 * 32 + quad * 8];
        O[t] = MFMA16(ap, bv, O[t]);
      }
    }
  }

#pragma unroll
  for (int t = 0; t < 8; t++)
#pragma unroll
    for (int r = 0; r < 4; r++) {
      int q = q0 + quad * 4 + r;
      ctx[(size_t)(b * 2048 + q) * 128 + t * 16 + l16] = (_Float16)(O[t][r] / l_r[r]);
    }
}

// ---------------------------------------------------------------------------
// Kernel 4: out projection ctx[8192,128] x wo[128,1024] -> fp32 out.
// Single K=128 pass, one barrier. Grid (128 m-tiles, 8 n-tiles).
// ---------------------------------------------------------------------------
__global__ __launch_bounds__(256) void out_gemm(
    const _Float16* __restrict__ ctx, const _Float16* __restrict__ wot,
    float* __restrict__ out) {
  __shared__ _Float16 A_lds[64 * 136];
  __shared__ _Float16 B_lds[128 * 136];
  int tid = threadIdx.x;
  int w = tid >> 6, lane = tid & 63, quad = lane >> 4, l16 = lane & 15;
  int m0 = blockIdx.x * 64, n0 = blockIdx.y * 128;
  {
    int row = tid >> 2, kk = (tid & 3) * 32;
#pragma unroll
    for (int i = 0; i < 4; i++)
      *(half8*)&A_lds[row * 136 + kk + i * 8] =
          *(const half8*)&ctx[(size_t)(m0 + row) * 128 + kk + i * 8];
  }
  {
    int n = tid >> 1, kk = (tid & 1) * 64;
#pragma unroll
    for (int i = 0; i < 8; i++)
      *(half8*)&B_lds[n * 136 + kk + i * 8] =
          *(const half8*)&wot[(size_t)(n0 + n) * 128 + kk + i * 8];
  }
  __syncthreads();
  floatx4 zero = {0.f, 0.f, 0.f, 0.f};
  floatx4 acc[8];
#pragma unroll
  for (int t = 0; t < 8; t++) acc[t] = zero;
  half8 a[4];
#pragma unroll
  for (int c = 0; c < 4; c++) a[c] = *(const half8*)&A_lds[(w * 16 + l16) * 136 + c * 32 + quad * 8];
#pragma unroll
  for (int t = 0; t < 8; t++)
#pragma unroll
    for (int c = 0; c < 4; c++) {
      half8 b = *(const half8*)&B_lds[(t * 16 + l16) * 136 + c * 32 + quad * 8];
      acc[t] = MFMA16(a[c], b, acc[t]);
    }
#pragma unroll
  for (int t = 0; t < 8; t++)
#pragma unroll
    for (int r = 0; r < 4; r++) {
      int row = m0 + w * 16 + quad * 4 + r;
      out[(size_t)row * 1024 + n0 + t * 16 + l16] = acc[t][r];
    }
}

// ---------------------------------------------------------------------------
extern "C" void kernel_launch(void* const* d_in, const int* in_sizes, int n_in,
                              void* d_out, int out_size, void* d_ws, size_t ws_size,
                              hipStream_t stream) {
  const float* x = (const float*)d_in[0];
  const float* wq = (const float*)d_in[1];
  const float* wk = (const float*)d_in[2];
  const float* wv = (const float*)d_in[3];
  const float* wo = (const float*)d_in[4];
  char* ws = (char*)d_ws;
  _Float16* wqt = (_Float16*)(ws + 0);
  _Float16* wkt = (_Float16*)(ws + 262144);
  _Float16* wvt = (_Float16*)(ws + 524288);
  _Float16* wot = (_Float16*)(ws + 786432);
  _Float16* Qh  = (_Float16*)(ws + 1048576);
  _Float16* Kh  = (_Float16*)(ws + 1048576 + 2097152);
  _Float16* Vt  = (_Float16*)(ws + 1048576 + 2 * 2097152);
  _Float16* ctxh = (_Float16*)(ws + 1048576 + 3 * 2097152);
  float* out = (float*)d_out;

  transpose_convert<<<512, 256, 0, stream>>>(wq, wk, wv, wo, wqt, wkt, wvt, wot);
  qkv_gemm<<<dim3(128, 3), 256, 0, stream>>>(x, wqt, wkt, wvt, Qh, Kh, Vt);
  attn<<<512, 64, 0, stream>>>(Qh, Kh, Vt, ctxh);
  out_gemm<<<dim3(128, 8), 256, 0, stream>>>(ctxh, wot, out);
}

// Round 3
// 171.633 us; speedup vs baseline: 1.7653x; 1.7653x over previous
//
#include <hip/hip_runtime.h>
#include <hip/hip_bf16.h>

typedef _Float16 half8 __attribute__((ext_vector_type(8)));
typedef _Float16 half4_t __attribute__((ext_vector_type(4)));
typedef _Float16 half2_t __attribute__((ext_vector_type(2)));
typedef float floatx4 __attribute__((ext_vector_type(4)));

#define MFMA16(a, b, c) __builtin_amdgcn_mfma_f32_16x16x32_f16(a, b, c, 0, 0, 0)
#define MASKVAL (-30000.0f)

// 1/sqrt(128) * log2(e): scores land in log2 domain -> softmax uses exp2f
#define QSCALE 0.1275261529f

// ---------------------------------------------------------------------------
// Kernel 1: coalesced LDS-tiled transpose + fp32->fp16 convert.
// ---------------------------------------------------------------------------
__global__ __launch_bounds__(256) void transpose_convert(
    const float* __restrict__ wq, const float* __restrict__ wk,
    const float* __restrict__ wv, const float* __restrict__ wo,
    _Float16* __restrict__ wqt, _Float16* __restrict__ wkt,
    _Float16* __restrict__ wvt, _Float16* __restrict__ wot) {
  __shared__ float T[32][36];
  int bx = blockIdx.x, tid = threadIdx.x;
  const float* src;
  _Float16* dst;
  int R, C, r0, c0;
  if (bx < 384) {
    int p = bx >> 7, t = bx & 127;
    src = (p == 0) ? wq : (p == 1) ? wk : wv;
    dst = (p == 0) ? wqt : (p == 1) ? wkt : wvt;
    R = 1024; C = 128;
    r0 = (t & 31) * 32; c0 = (t >> 5) * 32;
  } else {
    int t = bx - 384;
    src = wo; dst = wot;
    R = 128; C = 1024;
    r0 = (t & 3) * 32; c0 = (t >> 2) * 32;
  }
  {
    int row = tid >> 3, c4 = (tid & 7) * 4;
    float4 f = *(const float4*)&src[(size_t)(r0 + row) * C + c0 + c4];
    T[row][c4] = f.x; T[row][c4 + 1] = f.y; T[row][c4 + 2] = f.z; T[row][c4 + 3] = f.w;
  }
  __syncthreads();
  {
    int cc = tid >> 3, r4 = (tid & 7) * 4;
    half4_t h;
    h[0] = (_Float16)T[r4 + 0][cc];
    h[1] = (_Float16)T[r4 + 1][cc];
    h[2] = (_Float16)T[r4 + 2][cc];
    h[3] = (_Float16)T[r4 + 3][cc];
    *(half4_t*)&dst[(size_t)(c0 + cc) * R + r0 + r4] = h;
  }
}

// ---------------------------------------------------------------------------
// Kernel 2: QKV projection, grid (128 m-tiles, 3 proj). Q pre-scaled, V
// written transposed Vt[(b*128+h)*2048+s].
// ---------------------------------------------------------------------------
__global__ __launch_bounds__(256) void qkv_gemm(
    const float* __restrict__ x, const _Float16* __restrict__ wqt,
    const _Float16* __restrict__ wkt, const _Float16* __restrict__ wvt,
    _Float16* __restrict__ Qh, _Float16* __restrict__ Kh,
    _Float16* __restrict__ Vt) {
  __shared__ _Float16 A_lds[64 * 72];
  __shared__ _Float16 B_lds[128 * 72];
  int tid = threadIdx.x;
  int w = tid >> 6, lane = tid & 63, quad = lane >> 4, l16 = lane & 15;
  int m0 = blockIdx.x * 64;
  int proj = blockIdx.y;
  const _Float16* wt = (proj == 0) ? wqt : (proj == 1) ? wkt : wvt;
  floatx4 zero = {0.f, 0.f, 0.f, 0.f};
  floatx4 acc[8];
#pragma unroll
  for (int t = 0; t < 8; t++) acc[t] = zero;

  int arow = tid >> 2, akk = (tid & 3) * 16;
  int bn = tid >> 1, bkk = (tid & 1) * 32;

  for (int k0 = 0; k0 < 1024; k0 += 64) {
    {
      const float* s = x + (size_t)(m0 + arow) * 1024 + k0 + akk;
      float4 f0 = *(const float4*)(s);
      float4 f1 = *(const float4*)(s + 4);
      float4 f2 = *(const float4*)(s + 8);
      float4 f3 = *(const float4*)(s + 12);
      half8 h0, h1;
      h0[0] = (_Float16)f0.x; h0[1] = (_Float16)f0.y; h0[2] = (_Float16)f0.z; h0[3] = (_Float16)f0.w;
      h0[4] = (_Float16)f1.x; h0[5] = (_Float16)f1.y; h0[6] = (_Float16)f1.z; h0[7] = (_Float16)f1.w;
      h1[0] = (_Float16)f2.x; h1[1] = (_Float16)f2.y; h1[2] = (_Float16)f2.z; h1[3] = (_Float16)f2.w;
      h1[4] = (_Float16)f3.x; h1[5] = (_Float16)f3.y; h1[6] = (_Float16)f3.z; h1[7] = (_Float16)f3.w;
      *(half8*)&A_lds[arow * 72 + akk] = h0;
      *(half8*)&A_lds[arow * 72 + akk + 8] = h1;
    }
#pragma unroll
    for (int i = 0; i < 4; i++)
      *(half8*)&B_lds[bn * 72 + bkk + i * 8] =
          *(const half8*)&wt[(size_t)bn * 1024 + k0 + bkk + i * 8];
    __syncthreads();
    half8 a[2];
#pragma unroll
    for (int c = 0; c < 2; c++) a[c] = *(const half8*)&A_lds[(w * 16 + l16) * 72 + c * 32 + quad * 8];
#pragma unroll
    for (int t = 0; t < 8; t++)
#pragma unroll
      for (int c = 0; c < 2; c++) {
        half8 b = *(const half8*)&B_lds[(t * 16 + l16) * 72 + c * 32 + quad * 8];
        acc[t] = MFMA16(a[c], b, acc[t]);
      }
    __syncthreads();
  }
#pragma unroll
  for (int t = 0; t < 8; t++)
#pragma unroll
    for (int r = 0; r < 4; r++) {
      int row = m0 + w * 16 + quad * 4 + r;
      int col = t * 16 + l16;
      float v = acc[t][r];
      if (proj == 0)
        Qh[(size_t)row * 128 + col] = (_Float16)(v * QSCALE);
      else if (proj == 1)
        Kh[(size_t)row * 128 + col] = (_Float16)v;
      else {
        int bb = row >> 11, s = row & 2047;
        Vt[((size_t)(bb * 128 + col)) * 2048 + s] = (_Float16)v;
      }
    }
}

// ---------------------------------------------------------------------------
// Kernel 3: split-K flash attention partial. Grid (8 kchunk, 32 qtile rev, 4 b),
// block = 4 waves, each wave owns 16 queries. Chunk = 256 keys as 4 subtiles
// of 64 staged in LDS. Writes unnormalized O (fp16) + m,l (fp32) per chunk.
// ---------------------------------------------------------------------------
__global__ __launch_bounds__(256) void attn_partial(
    const _Float16* __restrict__ Qh, const _Float16* __restrict__ Kh,
    const _Float16* __restrict__ Vt, _Float16* __restrict__ Opart,
    float* __restrict__ Ml) {
  __shared__ _Float16 K_lds[64 * 136];   // 64 keys x 128 f, stride 136
  __shared__ _Float16 V_lds[128 * 72];   // 128 heads x 64 keys, stride 72
  __shared__ _Float16 P_lds[4 * 16 * 76];
  int tid = threadIdx.x;
  int w = tid >> 6, lane = tid & 63, quad = lane >> 4, l16 = lane & 15;
  int kc = blockIdx.x;
  int qt = 31 - (int)blockIdx.y;  // heavy q-tiles dispatch first
  int b = blockIdx.z;
  int q0 = qt * 64;
  int nkc = (q0 + 319) >> 8;
  if (kc >= nkc) return;
  int sidx = (b * 32 + qt) * 8 + kc;
  int ks0 = kc * 256;
  int kend = ks0 + 256 < q0 + 64 ? ks0 + 256 : q0 + 64;
  int qw0 = q0 + w * 16;

  const _Float16* Kb = Kh + (size_t)b * 2048 * 128;
  const _Float16* Vb = Vt + (size_t)b * 128 * 2048;

  half8 aq[4];
  {
    const _Float16* qbase = Qh + (size_t)(b * 2048 + qw0 + l16) * 128;
#pragma unroll
    for (int c = 0; c < 4; c++) aq[c] = *(const half8*)&qbase[c * 32 + quad * 8];
  }

  float m_r[4], l_r[4];
  floatx4 zero = {0.f, 0.f, 0.f, 0.f};
  floatx4 O[8];
#pragma unroll
  for (int r = 0; r < 4; r++) { m_r[r] = MASKVAL; l_r[r] = 0.f; }
#pragma unroll
  for (int t = 0; t < 8; t++) O[t] = zero;

  int krow = tid >> 2, kof = (tid & 3) * 32;
  int vh = tid & 127, vof = (tid >> 7) * 32;

  for (int ks = ks0; ks < kend; ks += 64) {
#pragma unroll
    for (int i = 0; i < 4; i++)
      *(half8*)&K_lds[krow * 136 + kof + i * 8] =
          *(const half8*)&Kb[(size_t)(ks + krow) * 128 + kof + i * 8];
#pragma unroll
    for (int i = 0; i < 4; i++)
      *(half8*)&V_lds[vh * 72 + vof + i * 8] =
          *(const half8*)&Vb[(size_t)vh * 2048 + ks + vof + i * 8];
    __syncthreads();

    if (ks <= qw0) {  // wave-uniform: skip subtiles entirely above our queries
      floatx4 sa[4];
#pragma unroll
      for (int t = 0; t < 4; t++) sa[t] = zero;
#pragma unroll
      for (int t = 0; t < 4; t++)
#pragma unroll
        for (int c = 0; c < 4; c++) {
          half8 bk = *(const half8*)&K_lds[(t * 16 + l16) * 136 + c * 32 + quad * 8];
          sa[t] = MFMA16(aq[c], bk, sa[t]);
        }

      bool domask = (ks + 63 > qw0);
      float p[4][4];
#pragma unroll
      for (int r = 0; r < 4; r++) {
        int query = qw0 + quad * 4 + r;
        float mx = m_r[r];
#pragma unroll
        for (int t = 0; t < 4; t++) {
          float s = sa[t][r];
          if (domask && (ks + t * 16 + l16 > query)) s = MASKVAL;
          p[t][r] = s;
          mx = fmaxf(mx, s);
        }
#pragma unroll
        for (int off = 1; off < 16; off <<= 1) mx = fmaxf(mx, __shfl_xor(mx, off));
        float alpha = exp2f(m_r[r] - mx);
        float rs = 0.f;
#pragma unroll
        for (int t = 0; t < 4; t++) {
          float e = exp2f(p[t][r] - mx);
          p[t][r] = e;
          rs += e;
        }
#pragma unroll
        for (int off = 1; off < 16; off <<= 1) rs += __shfl_xor(rs, off);
        l_r[r] = alpha * l_r[r] + rs;
        m_r[r] = mx;
#pragma unroll
        for (int t = 0; t < 8; t++) O[t][r] *= alpha;
      }

      // P: C-layout -> LDS -> A-layout (wave-private region)
#pragma unroll
      for (int r = 0; r < 4; r++)
#pragma unroll
        for (int t = 0; t < 4; t++)
          P_lds[w * 16 * 76 + (quad * 4 + r) * 76 + t * 16 + l16] = (_Float16)p[t][r];

#pragma unroll
      for (int c2 = 0; c2 < 2; c2++) {
        half8 ap = *(const half8*)&P_lds[w * 16 * 76 + l16 * 76 + c2 * 32 + quad * 8];
#pragma unroll
        for (int t = 0; t < 8; t++) {
          half8 bv = *(const half8*)&V_lds[(t * 16 + l16) * 72 + c2 * 32 + quad * 8];
          O[t] = MFMA16(ap, bv, O[t]);
        }
      }
    }
    __syncthreads();
  }

  size_t obase = (size_t)sidx * 8192;
#pragma unroll
  for (int t = 0; t < 8; t++)
#pragma unroll
    for (int r = 0; r < 4; r++)
      Opart[obase + (size_t)(w * 16 + quad * 4 + r) * 128 + t * 16 + l16] = (_Float16)O[t][r];
  if (l16 == 0)
#pragma unroll
    for (int r = 0; r < 4; r++) {
      int row = w * 16 + quad * 4 + r;
      Ml[(size_t)sidx * 128 + row * 2] = m_r[r];
      Ml[(size_t)sidx * 128 + row * 2 + 1] = l_r[r];
    }
}

// ---------------------------------------------------------------------------
// Kernel 3b: combine partials. One wave per query row; lane owns 2 features.
// ---------------------------------------------------------------------------
__global__ __launch_bounds__(256) void attn_combine(
    const _Float16* __restrict__ Opart, const float* __restrict__ Ml,
    _Float16* __restrict__ ctx) {
  int tid = threadIdx.x;
  int w = tid >> 6, lane = tid & 63;
  int row = blockIdx.x * 4 + w;  // 0..8191
  int b = row >> 11, s = row & 2047;
  int qt = s >> 6, ri = s & 63;
  int nkc = (qt * 64 + 319) >> 8;
  int sidx0 = (b * 32 + qt) * 8;
  float m[8], l[8];
  float M = MASKVAL;
  for (int i = 0; i < nkc; i++) {
    m[i] = Ml[(size_t)(sidx0 + i) * 128 + ri * 2];
    l[i] = Ml[(size_t)(sidx0 + i) * 128 + ri * 2 + 1];
    M = fmaxf(M, m[i]);
  }
  float L = 0.f, sc[8];
  for (int i = 0; i < nkc; i++) {
    sc[i] = exp2f(m[i] - M);
    L += l[i] * sc[i];
  }
  float inv = 1.f / L;
  float a0 = 0.f, a1 = 0.f;
  for (int i = 0; i < nkc; i++) {
    half2_t o = *(const half2_t*)&Opart[(size_t)(sidx0 + i) * 8192 + (size_t)ri * 128 + lane * 2];
    a0 += sc[i] * (float)o[0];
    a1 += sc[i] * (float)o[1];
  }
  half2_t hv;
  hv[0] = (_Float16)(a0 * inv);
  hv[1] = (_Float16)(a1 * inv);
  *(half2_t*)&ctx[(size_t)row * 128 + lane * 2] = hv;
}

// ---------------------------------------------------------------------------
// Kernel 4: out projection ctx[8192,128] x wo[128,1024] -> fp32 out.
// ---------------------------------------------------------------------------
__global__ __launch_bounds__(256) void out_gemm(
    const _Float16* __restrict__ ctx, const _Float16* __restrict__ wot,
    float* __restrict__ out) {
  __shared__ _Float16 A_lds[64 * 136];
  __shared__ _Float16 B_lds[128 * 136];
  int tid = threadIdx.x;
  int w = tid >> 6, lane = tid & 63, quad = lane >> 4, l16 = lane & 15;
  int m0 = blockIdx.x * 64, n0 = blockIdx.y * 128;
  {
    int row = tid >> 2, kk = (tid & 3) * 32;
#pragma unroll
    for (int i = 0; i < 4; i++)
      *(half8*)&A_lds[row * 136 + kk + i * 8] =
          *(const half8*)&ctx[(size_t)(m0 + row) * 128 + kk + i * 8];
  }
  {
    int n = tid >> 1, kk = (tid & 1) * 64;
#pragma unroll
    for (int i = 0; i < 8; i++)
      *(half8*)&B_lds[n * 136 + kk + i * 8] =
          *(const half8*)&wot[(size_t)(n0 + n) * 128 + kk + i * 8];
  }
  __syncthreads();
  floatx4 zero = {0.f, 0.f, 0.f, 0.f};
  floatx4 acc[8];
#pragma unroll
  for (int t = 0; t < 8; t++) acc[t] = zero;
  half8 a[4];
#pragma unroll
  for (int c = 0; c < 4; c++) a[c] = *(const half8*)&A_lds[(w * 16 + l16) * 136 + c * 32 + quad * 8];
#pragma unroll
  for (int t = 0; t < 8; t++)
#pragma unroll
    for (int c = 0; c < 4; c++) {
      half8 b = *(const half8*)&B_lds[(t * 16 + l16) * 136 + c * 32 + quad * 8];
      acc[t] = MFMA16(a[c], b, acc[t]);
    }
#pragma unroll
  for (int t = 0; t < 8; t++)
#pragma unroll
    for (int r = 0; r < 4; r++) {
      int row = m0 + w * 16 + quad * 4 + r;
      out[(size_t)row * 1024 + n0 + t * 16 + l16] = acc[t][r];
    }
}

// ---------------------------------------------------------------------------
extern "C" void kernel_launch(void* const* d_in, const int* in_sizes, int n_in,
                              void* d_out, int out_size, void* d_ws, size_t ws_size,
                              hipStream_t stream) {
  const float* x = (const float*)d_in[0];
  const float* wq = (const float*)d_in[1];
  const float* wk = (const float*)d_in[2];
  const float* wv = (const float*)d_in[3];
  const float* wo = (const float*)d_in[4];
  char* ws = (char*)d_ws;
  _Float16* wqt = (_Float16*)(ws + 0);
  _Float16* wkt = (_Float16*)(ws + 262144);
  _Float16* wvt = (_Float16*)(ws + 524288);
  _Float16* wot = (_Float16*)(ws + 786432);
  _Float16* Qh  = (_Float16*)(ws + 1048576);
  _Float16* Kh  = (_Float16*)(ws + 1048576 + 2097152);
  _Float16* Vt  = (_Float16*)(ws + 1048576 + 2 * 2097152);
  _Float16* ctxh = (_Float16*)(ws + 1048576 + 3 * 2097152);
  _Float16* Opart = (_Float16*)(ws + 9437184);            // 1024 x 64 x 128 fp16 = 16 MB
  float* Ml = (float*)(ws + 9437184 + 16777216);          // 1024 x 64 x 2 fp32 = 512 KB
  float* out = (float*)d_out;

  transpose_convert<<<512, 256, 0, stream>>>(wq, wk, wv, wo, wqt, wkt, wvt, wot);
  qkv_gemm<<<dim3(128, 3), 256, 0, stream>>>(x, wqt, wkt, wvt, Qh, Kh, Vt);
  attn_partial<<<dim3(8, 32, 4), 256, 0, stream>>>(Qh, Kh, Vt, Opart, Ml);
  attn_combine<<<2048, 256, 0, stream>>>(Opart, Ml, ctxh);
  out_gemm<<<dim3(128, 8), 256, 0, stream>>>(ctxh, wot, out);
}